// Round 5
// baseline (407.219 us; speedup 1.0000x reference)
//
#include <hip/hip_runtime.h>
#include <hip/hip_bf16.h>
#include <cstdint>
#include <cstddef>

// MultiHeadAttention: fp32 in/out. B=4, L=2048, D=1024, H=16, dk=64.
// bf16 MFMA internally, fp32 accumulation. 4 dispatches:
// wtrans -> fused QKV GEMM (fp32 A staged, cvt in-kernel) -> flash-attn -> out GEMM.

typedef unsigned short u16;
typedef __bf16 bf8v __attribute__((ext_vector_type(8)));   // MFMA A/B frag (4 VGPRs)
typedef __bf16 bf4v __attribute__((ext_vector_type(4)));
typedef float f32x4 __attribute__((ext_vector_type(4)));   // MFMA C/D frag

#define D_MODEL 1024
#define NHEAD   16
#define DK      64
#define BATCH   4
#define SEQ     2048
#define ROWS    (BATCH * SEQ)   // 8192

__device__ __forceinline__ u16 f2b(float f) {  // RTNE float->bf16
  union { float f; unsigned int i; } x; x.f = f;
  unsigned int r = x.i + 0x7fffu + ((x.i >> 16) & 1u);
  return (u16)(r >> 16);
}
__device__ __forceinline__ ushort4 pack4(float a, float b, float c, float d) {
  union { bf4v v; ushort4 u; } x;
  x.v[0] = (__bf16)a; x.v[1] = (__bf16)b; x.v[2] = (__bf16)c; x.v[3] = (__bf16)d;
  return x.u;
}
__device__ __forceinline__ void async16(const void* g, void* l) {
  __builtin_amdgcn_global_load_lds((const __attribute__((address_space(1))) void*)g,
                                   (__attribute__((address_space(3))) void*)l, 16, 0, 0);
}
#define MFMA16(a, b, c) __builtin_amdgcn_mfma_f32_16x16x32_bf16(a, b, c, 0, 0, 0)

// -------- weight transpose + downcast: dst[n][k] = bf16(src[k][n]), 4 mats ------
__global__ void wtrans_cvt_kernel(const float* __restrict__ w0, const float* __restrict__ w1,
                                  const float* __restrict__ w2, const float* __restrict__ w3,
                                  u16* __restrict__ dst4) {
  __shared__ float t[32][33];
  const float* src = (blockIdx.z == 0) ? w0 : (blockIdx.z == 1) ? w1
                   : (blockIdx.z == 2) ? w2 : w3;
  u16* dst = dst4 + (size_t)blockIdx.z * D_MODEL * D_MODEL;
  const int c0 = blockIdx.x * 32, r0 = blockIdx.y * 32;
  for (int i = threadIdx.y; i < 32; i += 8)
    t[i][threadIdx.x] = src[(size_t)(r0 + i) * D_MODEL + c0 + threadIdx.x];
  __syncthreads();
  for (int i = threadIdx.y; i < 32; i += 8)
    dst[(size_t)(c0 + i) * D_MODEL + r0 + threadIdx.x] = f2b(t[threadIdx.x][i]);
}

// ---- shared GEMM epilogue: C layout col=lane&15, row=quad*4+reg [m89] ----------
// mode 0: out bf16 [bh][l][dk]; mode 1: out bf16 [bh][dk][l]; mode 2: out fp32.
__device__ __forceinline__ void gemm_epilogue(const f32x4 acc[4][4],
                                              const float* __restrict__ bias,
                                              void* __restrict__ out, int mode,
                                              float oscale, int m0, int n0,
                                              int wm, int wn, int quad, int l16) {
#pragma unroll
  for (int j = 0; j < 4; j++) {
    const int n = n0 + wn * 64 + j * 16 + l16;
    const float bv = bias[n];
#pragma unroll
    for (int i = 0; i < 4; i++) {
      const int gr0 = m0 + wm * 64 + i * 16 + quad * 4;
#pragma unroll
      for (int r = 0; r < 4; r++) {
        const int row = gr0 + r;
        const float val = (acc[i][j][r] + bv) * oscale;
        if (mode == 2) {
          ((float*)out)[(size_t)row * D_MODEL + n] = val;
        } else {
          const int b = row >> 11, l = row & 2047;
          const int h = n >> 6, d = n & 63;
          if (mode == 0)
            ((u16*)out)[(((size_t)(b * NHEAD + h) * SEQ + l) << 6) + d] = f2b(val);
          else
            ((u16*)out)[(((size_t)(b * NHEAD + h) * DK + d) << 11) + l] = f2b(val);
        }
      }
    }
  }
}

#define BM 128
#define BN 128
#define BK 32

// ---------- fused QKV projection: grid.z selects (A, W^T, bias, out, mode) ------
// A fp32 [8192,1024] staged directly into LDS (16 KB), cvt->bf16 at frag read.
// A-tile chunk swizzle: LDS[row][c] holds source k-chunk c^(row&7) (4 fp32/chunk).
__global__ __launch_bounds__(256) void gemm_qkv(const float* __restrict__ qa,
                                                const float* __restrict__ ka,
                                                const float* __restrict__ va,
                                                const u16* __restrict__ wt,
                                                const float* __restrict__ bq,
                                                const float* __restrict__ bk,
                                                const float* __restrict__ bv,
                                                u16* __restrict__ Qw, u16* __restrict__ Kw,
                                                u16* __restrict__ Vt, float qscale) {
  const int z = blockIdx.z;
  const float* A   = (z == 0) ? qa : (z == 1) ? ka : va;
  const u16* Bt    = wt + (size_t)z * D_MODEL * D_MODEL;
  const float* bia = (z == 0) ? bq : (z == 1) ? bk : bv;
  u16* out         = (z == 0) ? Qw : (z == 1) ? Kw : Vt;
  const int mode   = (z == 2) ? 1 : 0;
  const float osc  = (z == 0) ? qscale : 1.0f;

  __shared__ __align__(16) float Asf[BM * BK];  // 16 KB fp32 A-tile, chunk-swizzled
  __shared__ __align__(16) u16  Bs[BN * BK];    //  8 KB bf16 W^T tile
  const int tid = threadIdx.x;
  const int lane = tid & 63, wave = tid >> 6;
  const int wm = wave >> 1, wn = wave & 1;
  const int quad = lane >> 4, l16 = lane & 15;
  const int m0 = blockIdx.x * BM, n0 = blockIdx.y * BN;
  const int K = 1024;

  f32x4 acc[4][4];
#pragma unroll
  for (int i = 0; i < 4; i++)
#pragma unroll
    for (int j = 0; j < 4; j++) acc[i][j] = (f32x4){0.f, 0.f, 0.f, 0.f};

  // A staging: 4 rounds x (32 rows x 8 chunks of 4 fp32); source chunk xor row&7
  const int arow = tid >> 3, achk = tid & 7;
  const int aswz = (achk ^ (arow & 7)) * 4;
  const float* Ag = A + (size_t)(m0 + arow) * K + aswz;
  // B staging: as before (bf16, 2 rounds)
  const int brow = tid >> 2;
  const int bch = ((tid & 3) ^ ((tid >> 3) & 3)) * 8;
  const u16* Bg = Bt + (size_t)(n0 + brow) * K + bch;
  const int psw = l16 & 7;  // frag-read chunk swizzle key (row&7 == l16&7)
  const int fsw = (quad ^ ((l16 >> 1) & 3)) * 8;

  for (int k0 = 0; k0 < K; k0 += BK) {
    async16(Ag + k0,                    &Asf[tid * 4]);
    async16(Ag + (size_t)32 * K + k0,   &Asf[1024 + tid * 4]);
    async16(Ag + (size_t)64 * K + k0,   &Asf[2048 + tid * 4]);
    async16(Ag + (size_t)96 * K + k0,   &Asf[3072 + tid * 4]);
    async16(Bg + k0,                    &Bs[tid * 8]);
    async16(Bg + (size_t)64 * K + k0,   &Bs[2048 + tid * 8]);
    __syncthreads();

    bf8v af[4], bfr[4];
#pragma unroll
    for (int i = 0; i < 4; i++) {
      const int row = wm * 64 + i * 16 + l16;
      const f32x4 a0 = *(const f32x4*)&Asf[row * 32 + ((quad * 2 + 0) ^ psw) * 4];
      const f32x4 a1 = *(const f32x4*)&Asf[row * 32 + ((quad * 2 + 1) ^ psw) * 4];
      bf8v t;
      t[0] = (__bf16)a0[0]; t[1] = (__bf16)a0[1]; t[2] = (__bf16)a0[2]; t[3] = (__bf16)a0[3];
      t[4] = (__bf16)a1[0]; t[5] = (__bf16)a1[1]; t[6] = (__bf16)a1[2]; t[7] = (__bf16)a1[3];
      af[i] = t;
    }
#pragma unroll
    for (int j = 0; j < 4; j++)
      bfr[j] = *(const bf8v*)&Bs[(wn * 64 + j * 16 + l16) * BK + fsw];
#pragma unroll
    for (int i = 0; i < 4; i++)
#pragma unroll
      for (int j = 0; j < 4; j++)
        acc[i][j] = MFMA16(af[i], bfr[j], acc[i][j]);
    __syncthreads();
  }
  gemm_epilogue(acc, bia, out, mode, osc, m0, n0, wm, wn, quad, l16);
}

// ---------------- output GEMM: bf16 A (ctx) -> fp32 out ------------------------
__global__ __launch_bounds__(256) void gemm_bt(const u16* __restrict__ A,
                                               const u16* __restrict__ Bt,
                                               const float* __restrict__ bias,
                                               void* __restrict__ out, int mode,
                                               float oscale) {
  __shared__ __align__(16) u16 As[BM * BK];
  __shared__ __align__(16) u16 Bs[BN * BK];
  const int tid = threadIdx.x;
  const int lane = tid & 63, wave = tid >> 6;
  const int wm = wave >> 1, wn = wave & 1;
  const int quad = lane >> 4, l16 = lane & 15;
  const int m0 = blockIdx.x * BM, n0 = blockIdx.y * BN;
  const int K = 1024;

  f32x4 acc[4][4];
#pragma unroll
  for (int i = 0; i < 4; i++)
#pragma unroll
    for (int j = 0; j < 4; j++) acc[i][j] = (f32x4){0.f, 0.f, 0.f, 0.f};

  const int srow = tid >> 2;
  const int sch = ((tid & 3) ^ ((tid >> 3) & 3)) * 8;
  const int fsw = (quad ^ ((l16 >> 1) & 3)) * 8;
  const u16* Ag = A + (size_t)(m0 + srow) * K + sch;
  const u16* Bg = Bt + (size_t)(n0 + srow) * K + sch;

  for (int k0 = 0; k0 < K; k0 += BK) {
    async16(Ag + k0, &As[tid * 8]);
    async16(Ag + (size_t)64 * K + k0, &As[2048 + tid * 8]);
    async16(Bg + k0, &Bs[tid * 8]);
    async16(Bg + (size_t)64 * K + k0, &Bs[2048 + tid * 8]);
    __syncthreads();

    bf8v af[4], bfr[4];
#pragma unroll
    for (int i = 0; i < 4; i++)
      af[i] = *(const bf8v*)&As[(wm * 64 + i * 16 + l16) * BK + fsw];
#pragma unroll
    for (int j = 0; j < 4; j++)
      bfr[j] = *(const bf8v*)&Bs[(wn * 64 + j * 16 + l16) * BK + fsw];
#pragma unroll
    for (int i = 0; i < 4; i++)
#pragma unroll
      for (int j = 0; j < 4; j++)
        acc[i][j] = MFMA16(af[i], bfr[j], acc[i][j]);
    __syncthreads();
  }
  gemm_epilogue(acc, bias, out, mode, oscale, m0, n0, wm, wn, quad, l16);
}

// ---------------- flash attention (S^T form): block = 128 q rows x one bh -------
// Q,K: [bh][SEQ][DK] bf16, Q pre-scaled by 0.125*log2e.  Vt: [bh][DK][SEQ] bf16.
// ctx: [B*SEQ][D_MODEL] bf16.  P^T rows padded to 72 u16 (36 dwords) -> <=2-way
// bank aliasing on b64 writes / b128 reads without XOR.
__global__ __launch_bounds__(256, 3) void attn_kernel(const u16* __restrict__ Q,
                                                      const u16* __restrict__ K,
                                                      const u16* __restrict__ Vt,
                                                      u16* __restrict__ ctx) {
  const int bh = blockIdx.y;
  const int qb = blockIdx.x * 128;
  const int tid = threadIdx.x;
  const int lane = tid & 63, wave = tid >> 6;
  const int quad = lane >> 4, l16 = lane & 15;
  const u16* Qh = Q + (size_t)bh * SEQ * DK;
  const u16* Kh = K + (size_t)bh * SEQ * DK;
  const u16* Vh = Vt + (size_t)bh * DK * SEQ;

  __shared__ __align__(16) u16 Ks[2][2][64 * 32];  // 16 KB
  __shared__ __align__(16) u16 Vs[2][2][64 * 32];  // 16 KB
  __shared__ __align__(16) u16 Ps[4 * 32 * 72];    // 18 KB, padded rows

  const int srow = tid >> 2;
  const int sch  = ((tid & 3) ^ ((tid >> 3) & 3)) * 8;
  const int ldst = tid * 8;
  const int fsw  = (quad ^ ((l16 >> 1) & 3)) * 8;

  bf8v qf[2][2];
#pragma unroll
  for (int qg = 0; qg < 2; qg++)
#pragma unroll
    for (int h = 0; h < 2; h++)
      qf[qg][h] = *(const bf8v*)&Qh[(size_t)(qb + wave * 32 + qg * 16 + l16) * DK + h * 32 + quad * 8];

  f32x4 o[2][4];
  float m_q[2], l_q[2];
#pragma unroll
  for (int qg = 0; qg < 2; qg++) {
    m_q[qg] = -1e30f; l_q[qg] = 0.f;
#pragma unroll
    for (int d = 0; d < 4; d++) o[qg][d] = (f32x4){0.f, 0.f, 0.f, 0.f};
  }

  async16(Kh + (size_t)srow * DK + sch,       &Ks[0][0][ldst]);
  async16(Kh + (size_t)srow * DK + 32 + sch,  &Ks[0][1][ldst]);
  async16(Vh + (size_t)srow * SEQ + sch,      &Vs[0][0][ldst]);
  async16(Vh + (size_t)srow * SEQ + 32 + sch, &Vs[0][1][ldst]);
  __syncthreads();

  int p = 0;
  for (int kt = 0; kt < SEQ; kt += 64) {
    const int nt = kt + 64;
    if (nt < SEQ) {
      async16(Kh + (size_t)(nt + srow) * DK + sch,      &Ks[p ^ 1][0][ldst]);
      async16(Kh + (size_t)(nt + srow) * DK + 32 + sch, &Ks[p ^ 1][1][ldst]);
      async16(Vh + (size_t)srow * SEQ + nt + sch,       &Vs[p ^ 1][0][ldst]);
      async16(Vh + (size_t)srow * SEQ + nt + 32 + sch,  &Vs[p ^ 1][1][ldst]);
    }

    bf8v kf[4][2];
#pragma unroll
    for (int nb = 0; nb < 4; nb++)
#pragma unroll
      for (int h = 0; h < 2; h++)
        kf[nb][h] = *(const bf8v*)&Ks[p][h][(nb * 16 + l16) * 32 + fsw];

#pragma unroll
    for (int qg = 0; qg < 2; qg++) {
      // S^T: lane holds S[key = nb*16+quad*4+r][q = qg*16+l16]
      f32x4 s[4];
#pragma unroll
      for (int nb = 0; nb < 4; nb++) {
        f32x4 t = (f32x4){0.f, 0.f, 0.f, 0.f};
        t = MFMA16(kf[nb][0], qf[qg][0], t);
        t = MFMA16(kf[nb][1], qf[qg][1], t);
        s[nb] = t;
      }
      float mx = s[0][0];
#pragma unroll
      for (int nb = 0; nb < 4; nb++)
#pragma unroll
        for (int r = 0; r < 4; r++) mx = fmaxf(mx, s[nb][r]);
      mx = fmaxf(mx, __shfl_xor(mx, 16));
      mx = fmaxf(mx, __shfl_xor(mx, 32));
      const float Mo = m_q[qg];
      const float Mn = fmaxf(Mo, mx);
      m_q[qg] = Mn;
      const float al = __builtin_amdgcn_exp2f(Mo - Mn);
      float rs = 0.f;
#pragma unroll
      for (int nb = 0; nb < 4; nb++)
#pragma unroll
        for (int r = 0; r < 4; r++) {
          const float pv = __builtin_amdgcn_exp2f(s[nb][r] - Mn);
          s[nb][r] = pv;
          rs += pv;
        }
      rs += __shfl_xor(rs, 16);
      rs += __shfl_xor(rs, 32);
      l_q[qg] = l_q[qg] * al + rs;
      if (__ballot(Mn > Mo)) {  // skip O-rescale once running max is stable
#pragma unroll
        for (int d = 0; d < 4; d++) o[qg][d] *= al;
      }

      // P^T -> LDS, padded row (72 u16), plain key order
      const int prow = (wave * 32 + qg * 16 + l16) * 72;
#pragma unroll
      for (int nb = 0; nb < 4; nb++)
        *(ushort4*)&Ps[prow + nb * 16 + quad * 4] =
            pack4(s[nb][0], s[nb][1], s[nb][2], s[nb][3]);
    }

    // PV: O^T += V^T @ P^T
    bf8v vf[4][2], pf[2][2];
#pragma unroll
    for (int dc = 0; dc < 4; dc++)
#pragma unroll
      for (int kc = 0; kc < 2; kc++)
        vf[dc][kc] = *(const bf8v*)&Vs[p][kc][(dc * 16 + l16) * 32 + fsw];
#pragma unroll
    for (int qg = 0; qg < 2; qg++)
#pragma unroll
      for (int kc = 0; kc < 2; kc++)
        pf[qg][kc] = *(const bf8v*)&Ps[(wave * 32 + qg * 16 + l16) * 72 + kc * 32 + quad * 8];
#pragma unroll
    for (int qg = 0; qg < 2; qg++)
#pragma unroll
      for (int dc = 0; dc < 4; dc++) {
        o[qg][dc] = MFMA16(vf[dc][0], pf[qg][0], o[qg][dc]);
        o[qg][dc] = MFMA16(vf[dc][1], pf[qg][1], o[qg][dc]);
      }

    __syncthreads();
    p ^= 1;
  }

  const int b = bh >> 4, hh = bh & 15;
#pragma unroll
  for (int qg = 0; qg < 2; qg++) {
    const float inv = __builtin_amdgcn_rcpf(l_q[qg]);
    const int q = qb + wave * 32 + qg * 16 + l16;
#pragma unroll
    for (int dc = 0; dc < 4; dc++) {
      const int col = hh * 64 + dc * 16 + quad * 4;
      *(ushort4*)&ctx[(size_t)(b * SEQ + q) * D_MODEL + col] =
          pack4(o[qg][dc][0] * inv, o[qg][dc][1] * inv,
                o[qg][dc][2] * inv, o[qg][dc][3] * inv);
    }
  }
}

// -------------------------------- launch ---------------------------------------
extern "C" void kernel_launch(void* const* d_in, const int* in_sizes, int n_in,
                              void* d_out, int out_size, void* d_ws, size_t ws_size,
                              hipStream_t stream) {
  const float* q  = (const float*)d_in[0];
  const float* k  = (const float*)d_in[1];
  const float* v  = (const float*)d_in[2];
  const float* Wq = (const float*)d_in[3];
  const float* bq = (const float*)d_in[4];
  const float* Wk = (const float*)d_in[5];
  const float* bk = (const float*)d_in[6];
  const float* Wv = (const float*)d_in[7];
  const float* bv = (const float*)d_in[8];
  const float* Wo = (const float*)d_in[9];
  const float* bo = (const float*)d_in[10];

  u16* ws  = (u16*)d_ws;
  u16* wt  = ws;                                     // 4 x 1M bf16 (W^T x4) = 8 MB
  u16* ctx = wt + (size_t)4 * D_MODEL * D_MODEL;     // 16.8 MB
  u16* Qw  = ctx + (size_t)ROWS * D_MODEL;
  u16* Kw  = Qw + (size_t)ROWS * D_MODEL;
  u16* Vt  = Kw + (size_t)ROWS * D_MODEL;            // total ~75.6 MB

  const float QSCALE = 0.18033688011112042f;  // 0.125 * log2(e), exp2-domain softmax

  wtrans_cvt_kernel<<<dim3(32, 32, 4), dim3(32, 8), 0, stream>>>(Wq, Wk, Wv, Wo, wt);

  gemm_qkv<<<dim3(ROWS / BM, D_MODEL / BN, 3), 256, 0, stream>>>(
      q, k, v, wt, bq, bk, bv, Qw, Kw, Vt, QSCALE);

  attn_kernel<<<dim3(SEQ / 128, BATCH * NHEAD), 256, 0, stream>>>(Qw, Kw, Vt, ctx);

  gemm_bt<<<dim3(ROWS / BM, D_MODEL / BN), 256, 0, stream>>>(
      ctx, wt + (size_t)3 * D_MODEL * D_MODEL, bo, d_out, 2, 1.0f);
}